// Round 11
// baseline (1603.777 us; speedup 1.0000x reference)
//
#include <hip/hip_runtime.h>

typedef __attribute__((ext_vector_type(8))) short short8;
typedef __attribute__((ext_vector_type(4))) float floatx4;

#define NSTEPS 5
#define DD 512
#define ANN 256
#define NNODE 2048
#define NEDGE 8                 // 2*E
#define NCOLS (NNODE * NEDGE)   // 16384
#define MAXE 96                 // nnz per (node,edge-type): mean 30.7, sd 5.5
#define KP (NEDGE * DD)         // 4096

// Fragment-ordered (FO) layout for [M][K] bf16:
// addr(row,k) = ((row>>4)*(K>>3) + (k>>3))*128 + ((row&15)<<3) + (k&7)
// One slot = 16 rows x 32 k = 1KB, lane l's 16B at slot_base + l*16.

__device__ inline float bf2f(unsigned short s) {
    unsigned u = ((unsigned)s) << 16;
    float f; __builtin_memcpy(&f, &u, 4);
    return f;
}
__device__ inline unsigned short f2bf(float f) {   // round-to-nearest-even
    unsigned u; __builtin_memcpy(&u, &f, 4);
    u += 0x7fffu + ((u >> 16) & 1u);
    return (unsigned short)(u >> 16);
}
__device__ inline void split2(float x, unsigned short& hi, unsigned short& lo) {
    hi = f2bf(x);
    lo = f2bf(x - bf2f(hi));
}
// split-write one element into FO hi/lo planes (K=512)
__device__ inline void fo_write(short* __restrict__ Fhi, short* __restrict__ Flo,
                                int row, int col, float v) {
    unsigned short hs, ls;
    split2(v, hs, ls);
    size_t a = ((size_t)(row >> 4) * 64 + (col >> 3)) * 128 + ((row & 15) << 3) + (col & 7);
    Fhi[a] = (short)hs;
    Flo[a] = (short)ls;
}

// h = [ann | 0] fp32; HB (FO, K=512) = split(h); cnt2 = 0
__global__ __launch_bounds__(256) void k_init(const float* __restrict__ ann,
                                              float* __restrict__ h,
                                              short* __restrict__ HBhi,
                                              short* __restrict__ HBlo,
                                              int* __restrict__ cnt2) {
    int n = blockIdx.x, t = threadIdx.x;
    int c = 2 * t;
    float v0 = 0.f, v1 = 0.f;
    if (c < ANN) {
        v0 = ann[(size_t)n * ANN + c];
        v1 = ann[(size_t)n * ANN + c + 1];
    }
    h[(size_t)n * DD + c]     = v0;
    h[(size_t)n * DD + c + 1] = v1;
    unsigned short h0, l0, h1, l1;
    split2(v0, h0, l0);
    split2(v1, h1, l1);
    size_t a = ((size_t)(n >> 4) * 64 + (t >> 2)) * 128 + ((n & 15) << 3) + ((t & 3) << 1);
    *(unsigned*)(HBhi + a) = (unsigned)h0 | ((unsigned)h1 << 16);
    *(unsigned*)(HBlo + a) = (unsigned)l0 | ((unsigned)l1 << 16);
    if (t < NEDGE) cnt2[n * NEDGE + t] = 0;
}

// fp32 0/1 adjacency -> per-(row, edge-type) source-node index lists
__global__ __launch_bounds__(256) void k_build(const float* __restrict__ adj,
                                               int* __restrict__ cnt2,
                                               unsigned short* __restrict__ idx) {
    int n = blockIdx.x;
    const float* row = adj + (size_t)n * NCOLS;
    for (int j8 = threadIdx.x; j8 < NCOLS / 8; j8 += 256) {
        floatx4 a = *(const floatx4*)(row + j8 * 8);
        floatx4 b = *(const floatx4*)(row + j8 * 8 + 4);
        unsigned nz = 0;
        #pragma unroll
        for (int i = 0; i < 4; i++) {
            if (a[i] != 0.f) nz |= 1u << i;
            if (b[i] != 0.f) nz |= 1u << (4 + i);
        }
        while (nz) {
            int i = __builtin_ctz(nz);
            nz &= nz - 1;
            int j = j8 * 8 + i;
            int e = j >> 11;
            int m = j & (NNODE - 1);
            int p = atomicAdd(&cnt2[n * NEDGE + e], 1);
            if (p < MAXE) idx[((size_t)n * NEDGE + e) * MAXE + p] = (unsigned short)m;
        }
    }
}

// Transpose+split weights into FO (hi & lo), contiguous-K source [K][512]
__global__ __launch_bounds__(256) void k_transP(const float* __restrict__ W,
                                                short* __restrict__ Fhi,
                                                short* __restrict__ Flo, int K) {
    __shared__ float st[32][33];
    int tx = threadIdx.x & 31, ty = threadIdx.x >> 5;
    int k0 = blockIdx.x * 32, n0 = blockIdx.y * 32;
    #pragma unroll
    for (int i = 0; i < 4; i++)
        st[ty + i * 8][tx] = W[(size_t)(k0 + ty + i * 8) * DD + n0 + tx];
    __syncthreads();
    #pragma unroll
    for (int i = 0; i < 4; i++) {
        int n = n0 + ty + i * 8, k = k0 + tx;
        float v = st[tx][ty + i * 8];
        unsigned short hs, ls;
        split2(v, hs, ls);
        size_t a = ((size_t)(n >> 4) * (K >> 3) + (k >> 3)) * 128 + ((n & 15) << 3) + (k & 7);
        Fhi[a] = (short)hs;
        Flo[a] = (short)ls;
    }
}

// Same, 4-quadrant source (k-half x n-half), K=1024
__global__ __launch_bounds__(256) void k_transG(const float* __restrict__ s00,
                                                const float* __restrict__ s10,
                                                const float* __restrict__ s01,
                                                const float* __restrict__ s11,
                                                short* __restrict__ Fhi,
                                                short* __restrict__ Flo) {
    __shared__ float st[32][33];
    const int K = 2 * DD;
    int tx = threadIdx.x & 31, ty = threadIdx.x >> 5;
    int k0 = blockIdx.x * 32, n0 = blockIdx.y * 32;
    const float* sk0 = (n0 < DD) ? s00 : s01;
    const float* sk1 = (n0 < DD) ? s10 : s11;
    #pragma unroll
    for (int i = 0; i < 4; i++) {
        int k = k0 + ty + i * 8;
        const float* s = (k < DD) ? sk0 : sk1;
        st[ty + i * 8][tx] = s[(size_t)(k & (DD - 1)) * DD + ((n0 + tx) & (DD - 1))];
    }
    __syncthreads();
    #pragma unroll
    for (int i = 0; i < 4; i++) {
        int n = n0 + ty + i * 8, k = k0 + tx;
        float v = st[tx][ty + i * 8];
        unsigned short hs, ls;
        split2(v, hs, ls);
        size_t a = ((size_t)(n >> 4) * (K >> 3) + (k >> 3)) * 128 + ((n & 15) << 3) + (k & 7);
        Fhi[a] = (short)hs;
        Flo[a] = (short)ls;
    }
}

// All-edge gather (R10): 128 column-threads x 2 edge halves. Each thread does
// float4 loads over 4 edges (~123 x 16B, 8 in flight) -> FO split writes (nt).
// abuf = deg-weighted prop bias (eg==0 half).
__global__ __launch_bounds__(256) void k_gather_all(const float* __restrict__ h,
                                                    const int* __restrict__ cnt2,
                                                    const unsigned short* __restrict__ idx,
                                                    const float* __restrict__ bp,
                                                    short* __restrict__ Gbhi,
                                                    short* __restrict__ Gblo,
                                                    float* __restrict__ abuf) {
    __shared__ unsigned short sidx[NEDGE * MAXE];
    __shared__ int scnt[NEDGE];
    int n = blockIdx.x, t = threadIdx.x;

    if (t < NEDGE) scnt[t] = cnt2[n * NEDGE + t];
    for (int j = t; j < NEDGE * MAXE; j += 256)
        sidx[j] = idx[(size_t)n * NEDGE * MAXE + j];
    __syncthreads();

    const int th = t & 127;        // column group: cols 4*th .. 4*th+3
    const int eg = t >> 7;         // edge half: edges eg*4 .. eg*4+3
    // FO K=4096 write base: inner offset (n%16)*8 + (th&1)*4, kchunk = e*64 + th>>1
    size_t wbase = ((size_t)(n >> 4) * 512) * 128 + ((n & 15) << 3) + ((th & 1) << 2);

    #pragma unroll 1
    for (int ee = 0; ee < 4; ee++) {
        int e = eg * 4 + ee;
        int raw = scnt[e];
        int m = raw > MAXE ? MAXE : raw;
        const unsigned short* row = &sidx[e * MAXE];
        floatx4 a = (floatx4){0.f, 0.f, 0.f, 0.f};
        int i = 0;
        for (; i + 8 <= m; i += 8) {
            #pragma unroll
            for (int j = 0; j < 8; j++)
                a += *(const floatx4*)(h + (size_t)row[i + j] * DD + 4 * th);
        }
        for (; i < m; i++)
            a += *(const floatx4*)(h + (size_t)row[i] * DD + 4 * th);

        unsigned short hs[4], ls[4];
        #pragma unroll
        for (int j = 0; j < 4; j++) split2(a[j], hs[j], ls[j]);
        unsigned long long hp = (unsigned long long)hs[0] | ((unsigned long long)hs[1] << 16)
                              | ((unsigned long long)hs[2] << 32) | ((unsigned long long)hs[3] << 48);
        unsigned long long lp = (unsigned long long)ls[0] | ((unsigned long long)ls[1] << 16)
                              | ((unsigned long long)ls[2] << 32) | ((unsigned long long)ls[3] << 48);
        size_t addr = wbase + (size_t)(e * 64 + (th >> 1)) * 128;
        __builtin_nontemporal_store(hp, (unsigned long long*)(Gbhi + addr));
        __builtin_nontemporal_store(lp, (unsigned long long*)(Gblo + addr));
    }

    if (eg == 0) {
        floatx4 s = (floatx4){0.f, 0.f, 0.f, 0.f};
        #pragma unroll
        for (int e = 0; e < NEDGE; e++)
            s += (float)scnt[e] * *(const floatx4*)(bp + e * DD + 4 * th);
        __builtin_nontemporal_store(s, (floatx4*)(abuf + (size_t)n * DD + 4 * th));
    }
}

// Split-bf16 MFMA GEMM on FO operands: C = (Ahi+Alo)@(Bhi+Blo)^T (3 products), fp32 acc.
// Block 64(M)x64(N), 4 waves (2m x 2n), wave tile 32x32. BK=64, LDS dbuf (64 KB),
// 1 barrier/iter, VGPR staging. XCD-banded swizzle.
// MODE 0 (prop): K=4096, A=Gbig. v = acc + abuf[o]; Ga = split(v).
// MODE 1 (zr):   K=1024 (A seg: Ga|HB), N=1024. col<512: zbuf=sigmoid(v+b0);
//                else RH = split(sigmoid(v+b1)*h).
// MODE 2 (fin):  K=1024 (A seg: Ga|RH). hn=(1-z)h+z*tanh(v+b0); h, HB, outF.
template<int MODE>
__global__ __launch_bounds__(256, 2) void k_gemm7(
    const short* __restrict__ A0hi, const short* __restrict__ A0lo,
    const short* __restrict__ A1hi, const short* __restrict__ A1lo,
    const short* __restrict__ Bhi,  const short* __restrict__ Blo, int K,
    const float* __restrict__ bias0, const float* __restrict__ bias1,
    float* __restrict__ zbuf,
    float* __restrict__ h,
    short* __restrict__ Ohi, short* __restrict__ Olo,
    float* __restrict__ outF) {

    __shared__ short S[2][32][512];   // 2 bufs x 32 slots x 1KB = 64 KB

    const int tid = threadIdx.x;
    const int lane = tid & 63;
    const int wave = tid >> 6;
    const int wm = wave >> 1;          // m-half (32 rows)
    const int wn = wave & 1;           // n-half (32 cols)
    const int quad = lane >> 4;
    const int l16 = lane & 15;

    // XCD-banded swizzle (gridDim.y == 32 for all grids here)
    const int pbid = blockIdx.y * gridDim.x + blockIdx.x;
    const int bx = pbid >> 5;
    const int by = (pbid & 7) * 4 + ((pbid >> 3) & 3);
    const int blockM = by * 64;
    const int blockN = bx * 64;
    const int mt0 = blockM >> 4, nt0 = blockN >> 4;
    const int KCB = K >> 3;            // B kchunk stride

    floatx4 acc[2][2];
    #pragma unroll
    for (int mi = 0; mi < 2; mi++)
        #pragma unroll
        for (int ni = 0; ni < 2; ni++)
            acc[mi][ni] = (floatx4){0.f, 0.f, 0.f, 0.f};

    // slots: 0..7 A-hi (mt=u>>1, ks=u&1); 8..15 A-lo; 16..23 B-hi (nt, ks); 24..31 B-lo
    auto gaddr = [&](int k0, int s) -> const short* {
        if (s < 16) {
            int pl = s >> 3;           // 0 = hi, 1 = lo
            int u = s & 7;
            int mt = u >> 1, ks = u & 1;
            if (MODE == 0) {
                const short* base = pl ? A0lo : A0hi;
                return base + ((size_t)(mt0 + mt) * 512 + (k0 >> 3) + ks * 4) * 128;
            } else {
                int seg = k0 >> 9;
                const short* base = seg ? (pl ? A1lo : A1hi) : (pl ? A0lo : A0hi);
                return base + ((size_t)(mt0 + mt) * 64 + (((k0 & 511) >> 3) + ks * 4)) * 128;
            }
        } else {
            int u = s - 16;
            int pl = u >> 3;
            int v2 = u & 7;
            int nt = v2 >> 1, ks = v2 & 1;
            const short* base = pl ? Blo : Bhi;
            return base + ((size_t)(nt0 + nt) * KCB + (k0 >> 3) + ks * 4) * 128;
        }
    };

    short8 rg[8];
    #pragma unroll
    for (int j = 0; j < 8; j++)
        rg[j] = *(const short8*)(gaddr(0, wave * 8 + j) + lane * 8);
    #pragma unroll
    for (int j = 0; j < 8; j++)
        *(short8*)&S[0][wave * 8 + j][lane * 8] = rg[j];

    for (int k0 = 0; k0 < K; k0 += 64) {
        const int buf = (k0 >> 6) & 1;
        const bool more = (k0 + 64 < K);
        if (more) {
            #pragma unroll
            for (int j = 0; j < 8; j++)
                rg[j] = *(const short8*)(gaddr(k0 + 64, wave * 8 + j) + lane * 8);
        }
        __syncthreads();

        #pragma unroll
        for (int ks = 0; ks < 2; ks++) {
            short8 ah[2], al[2], bh[2], bl[2];
            #pragma unroll
            for (int mi = 0; mi < 2; mi++) {
                ah[mi] = *(const short8*)&S[buf][(wm * 2 + mi) * 2 + ks][lane * 8];
                al[mi] = *(const short8*)&S[buf][8 + (wm * 2 + mi) * 2 + ks][lane * 8];
            }
            #pragma unroll
            for (int ni = 0; ni < 2; ni++) {
                bh[ni] = *(const short8*)&S[buf][16 + (wn * 2 + ni) * 2 + ks][lane * 8];
                bl[ni] = *(const short8*)&S[buf][24 + (wn * 2 + ni) * 2 + ks][lane * 8];
            }
            #pragma unroll
            for (int mi = 0; mi < 2; mi++)
                #pragma unroll
                for (int ni = 0; ni < 2; ni++) {
                    acc[mi][ni] = __builtin_amdgcn_mfma_f32_16x16x32_bf16(ah[mi], bh[ni], acc[mi][ni], 0, 0, 0);
                    acc[mi][ni] = __builtin_amdgcn_mfma_f32_16x16x32_bf16(ah[mi], bl[ni], acc[mi][ni], 0, 0, 0);
                    acc[mi][ni] = __builtin_amdgcn_mfma_f32_16x16x32_bf16(al[mi], bh[ni], acc[mi][ni], 0, 0, 0);
                }
        }

        if (more) {
            #pragma unroll
            for (int j = 0; j < 8; j++)
                *(short8*)&S[buf ^ 1][wave * 8 + j][lane * 8] = rg[j];
        }
    }

    // C/D layout (m89-verified): elem r -> row = quad*4+r, col = l16
    #pragma unroll
    for (int mi = 0; mi < 2; mi++) {
        #pragma unroll
        for (int ni = 0; ni < 2; ni++) {
            int gcol = blockN + wn * 32 + ni * 16 + l16;
            #pragma unroll
            for (int r = 0; r < 4; r++) {
                int grow = blockM + wm * 32 + mi * 16 + quad * 4 + r;
                float v = acc[mi][ni][r];
                if (MODE == 0) {
                    size_t o = (size_t)grow * DD + gcol;
                    fo_write(Ohi, Olo, grow, gcol, v + zbuf[o]);
                } else if (MODE == 1) {
                    if (gcol < DD) {
                        size_t o = (size_t)grow * DD + gcol;
                        zbuf[o] = 1.f / (1.f + __expf(-(v + bias0[gcol])));
                    } else {
                        int c = gcol - DD;
                        size_t o = (size_t)grow * DD + c;
                        float rr = 1.f / (1.f + __expf(-(v + bias1[c])));
                        fo_write(Ohi, Olo, grow, c, rr * h[o]);
                    }
                } else {
                    size_t o = (size_t)grow * DD + gcol;
                    float zv = zbuf[o];
                    float hv = h[o];
                    float hn = (1.f - zv) * hv + zv * tanhf(v + bias0[gcol]);
                    h[o] = hn;
                    fo_write(Ohi, Olo, grow, gcol, hn);
                    outF[o] = hn;
                }
            }
        }
    }
}

extern "C" void kernel_launch(void* const* d_in, const int* in_sizes, int n_in,
                              void* d_out, int out_size, void* d_ws, size_t ws_size,
                              hipStream_t stream) {
    const float* adj = (const float*)d_in[0];
    const float* ann = (const float*)d_in[1];
    const float* Wp  = (const float*)d_in[2];
    const float* bp  = (const float*)d_in[3];
    const float* Wz  = (const float*)d_in[4];
    const float* Uz  = (const float*)d_in[5];
    const float* bz  = (const float*)d_in[6];
    const float* Wr  = (const float*)d_in[7];
    const float* Ur  = (const float*)d_in[8];
    const float* br  = (const float*)d_in[9];
    const float* Wh  = (const float*)d_in[10];
    const float* Uh  = (const float*)d_in[11];
    const float* bh  = (const float*)d_in[12];

    // workspace carve (~69 MB; ws ~512 MB per round-4 fill counters)
    char* p = (char*)d_ws;
    float* h     = (float*)p; p += (size_t)NNODE * DD * 4;          // 4 MB
    float* abuf  = (float*)p; p += (size_t)NNODE * DD * 4;          // 4 MB deg-bias -> z
    short* Gbhi  = (short*)p; p += (size_t)NNODE * KP * 2;          // 16 MB (FO K=4096)
    short* Gblo  = (short*)p; p += (size_t)NNODE * KP * 2;          // 16 MB
    short* Gahi  = (short*)p; p += (size_t)NNODE * DD * 2;          // 2 MB (FO K=512)
    short* Galo  = (short*)p; p += (size_t)NNODE * DD * 2;
    short* HBhi  = (short*)p; p += (size_t)NNODE * DD * 2;
    short* HBlo  = (short*)p; p += (size_t)NNODE * DD * 2;
    short* RHhi  = (short*)p; p += (size_t)NNODE * DD * 2;
    short* RHlo  = (short*)p; p += (size_t)NNODE * DD * 2;
    short* WpThi = (short*)p; p += (size_t)DD * KP * 2;             // 4 MB (FO N=512,K=4096)
    short* WpTlo = (short*)p; p += (size_t)DD * KP * 2;
    short* ZRhi  = (short*)p; p += (size_t)(2 * DD) * (2 * DD) * 2; // 2 MB (FO N=1024,K=1024)
    short* ZRlo  = (short*)p; p += (size_t)(2 * DD) * (2 * DD) * 2;
    short* HThi  = (short*)p; p += (size_t)DD * (2 * DD) * 2;       // 1 MB (FO N=512,K=1024)
    short* HTlo  = (short*)p; p += (size_t)DD * (2 * DD) * 2;
    unsigned short* idx = (unsigned short*)p;
    p += (size_t)NNODE * NEDGE * MAXE * 2;                          // 3 MB
    int* cnt2 = (int*)p; p += (size_t)NNODE * NEDGE * 4;

    float* outF = (float*)d_out;

    k_init<<<NNODE, 256, 0, stream>>>(ann, h, HBhi, HBlo, cnt2);
    k_build<<<NNODE, 256, 0, stream>>>(adj, cnt2, idx);
    k_transP<<<dim3(KP / 32, DD / 32), 256, 0, stream>>>(Wp, WpThi, WpTlo, KP);
    k_transG<<<dim3(32, 32), 256, 0, stream>>>(Wz, Uz, Wr, Ur, ZRhi, ZRlo);
    k_transG<<<dim3(32, 16), 256, 0, stream>>>(Wh, Uh, Wh, Uh, HThi, HTlo);

    dim3 gP(DD / 64, NNODE / 64);        // (8, 32)  = 256 blocks
    dim3 gZ(2 * DD / 64, NNODE / 64);    // (16, 32) = 512 blocks
    for (int s = 0; s < NSTEPS; s++) {
        k_gather_all<<<NNODE, 256, 0, stream>>>(h, cnt2, idx, bp, Gbhi, Gblo, abuf);
        // a = Gbig @ WpT + deg-bias -> Ga (FO hi/lo)
        k_gemm7<0><<<gP, 256, 0, stream>>>(Gbhi, Gblo, nullptr, nullptr,
                                           WpThi, WpTlo, KP, nullptr, nullptr,
                                           abuf, nullptr, Gahi, Galo, nullptr);
        // [z|r]: z -> abuf (fp32), RH = split(sigmoid(.)*h)
        k_gemm7<1><<<gZ, 256, 0, stream>>>(Gahi, Galo, HBhi, HBlo,
                                           ZRhi, ZRlo, 2 * DD, bz, br,
                                           abuf, h, RHhi, RHlo, nullptr);
        // h' = (1-z)h + z*tanh([a|rh]@[Wh;Uh]+bh) -> h, HB, d_out
        k_gemm7<2><<<gP, 256, 0, stream>>>(Gahi, Galo, RHhi, RHlo,
                                           HThi, HTlo, 2 * DD, bh, nullptr,
                                           abuf, h, HBhi, HBlo, outF);
    }
}

// Round 12
// 1534.433 us; speedup vs baseline: 1.0452x; 1.0452x over previous
//
#include <hip/hip_runtime.h>

typedef __attribute__((ext_vector_type(8))) short short8;
typedef __attribute__((ext_vector_type(4))) float floatx4;

#define NSTEPS 5
#define DD 512
#define ANN 256
#define NNODE 2048
#define NEDGE 8                 // 2*E
#define NCOLS (NNODE * NEDGE)   // 16384
#define MAXE 96                 // nnz per (node,edge-type): mean 30.7, sd 5.5
#define KP (NEDGE * DD)         // 4096

// Fragment-ordered (FO) layout for [M][K] bf16:
// addr(row,k) = ((row>>4)*(K>>3) + (k>>3))*128 + ((row&15)<<3) + (k&7)
// One slot = 16 rows x 32 k = 1KB, lane l's 16B at slot_base + l*16.

__device__ inline float bf2f(unsigned short s) {
    unsigned u = ((unsigned)s) << 16;
    float f; __builtin_memcpy(&f, &u, 4);
    return f;
}
__device__ inline unsigned short f2bf(float f) {   // round-to-nearest-even
    unsigned u; __builtin_memcpy(&u, &f, 4);
    u += 0x7fffu + ((u >> 16) & 1u);
    return (unsigned short)(u >> 16);
}
__device__ inline void split2(float x, unsigned short& hi, unsigned short& lo) {
    hi = f2bf(x);
    lo = f2bf(x - bf2f(hi));
}
// split-write one element into FO hi/lo planes (K=512)
__device__ inline void fo_write(short* __restrict__ Fhi, short* __restrict__ Flo,
                                int row, int col, float v) {
    unsigned short hs, ls;
    split2(v, hs, ls);
    size_t a = ((size_t)(row >> 4) * 64 + (col >> 3)) * 128 + ((row & 15) << 3) + (col & 7);
    Fhi[a] = (short)hs;
    Flo[a] = (short)ls;
}

// h = [ann | 0] fp32; HB (FO, K=512) = split(h); cnt2 = 0
__global__ __launch_bounds__(256) void k_init(const float* __restrict__ ann,
                                              float* __restrict__ h,
                                              short* __restrict__ HBhi,
                                              short* __restrict__ HBlo,
                                              int* __restrict__ cnt2) {
    int n = blockIdx.x, t = threadIdx.x;
    int c = 2 * t;
    float v0 = 0.f, v1 = 0.f;
    if (c < ANN) {
        v0 = ann[(size_t)n * ANN + c];
        v1 = ann[(size_t)n * ANN + c + 1];
    }
    h[(size_t)n * DD + c]     = v0;
    h[(size_t)n * DD + c + 1] = v1;
    unsigned short h0, l0, h1, l1;
    split2(v0, h0, l0);
    split2(v1, h1, l1);
    size_t a = ((size_t)(n >> 4) * 64 + (t >> 2)) * 128 + ((n & 15) << 3) + ((t & 3) << 1);
    *(unsigned*)(HBhi + a) = (unsigned)h0 | ((unsigned)h1 << 16);
    *(unsigned*)(HBlo + a) = (unsigned)l0 | ((unsigned)l1 << 16);
    if (t < NEDGE) cnt2[n * NEDGE + t] = 0;
}

// fp32 0/1 adjacency -> per-(row, edge-type) source-node index lists
__global__ __launch_bounds__(256) void k_build(const float* __restrict__ adj,
                                               int* __restrict__ cnt2,
                                               unsigned short* __restrict__ idx) {
    int n = blockIdx.x;
    const float* row = adj + (size_t)n * NCOLS;
    for (int j8 = threadIdx.x; j8 < NCOLS / 8; j8 += 256) {
        floatx4 a = *(const floatx4*)(row + j8 * 8);
        floatx4 b = *(const floatx4*)(row + j8 * 8 + 4);
        unsigned nz = 0;
        #pragma unroll
        for (int i = 0; i < 4; i++) {
            if (a[i] != 0.f) nz |= 1u << i;
            if (b[i] != 0.f) nz |= 1u << (4 + i);
        }
        while (nz) {
            int i = __builtin_ctz(nz);
            nz &= nz - 1;
            int j = j8 * 8 + i;
            int e = j >> 11;
            int m = j & (NNODE - 1);
            int p = atomicAdd(&cnt2[n * NEDGE + e], 1);
            if (p < MAXE) idx[((size_t)n * NEDGE + e) * MAXE + p] = (unsigned short)m;
        }
    }
}

// Transpose+split weights into FO (hi & lo), contiguous-K source [K][512]
__global__ __launch_bounds__(256) void k_transP(const float* __restrict__ W,
                                                short* __restrict__ Fhi,
                                                short* __restrict__ Flo, int K) {
    __shared__ float st[32][33];
    int tx = threadIdx.x & 31, ty = threadIdx.x >> 5;
    int k0 = blockIdx.x * 32, n0 = blockIdx.y * 32;
    #pragma unroll
    for (int i = 0; i < 4; i++)
        st[ty + i * 8][tx] = W[(size_t)(k0 + ty + i * 8) * DD + n0 + tx];
    __syncthreads();
    #pragma unroll
    for (int i = 0; i < 4; i++) {
        int n = n0 + ty + i * 8, k = k0 + tx;
        float v = st[tx][ty + i * 8];
        unsigned short hs, ls;
        split2(v, hs, ls);
        size_t a = ((size_t)(n >> 4) * (K >> 3) + (k >> 3)) * 128 + ((n & 15) << 3) + (k & 7);
        Fhi[a] = (short)hs;
        Flo[a] = (short)ls;
    }
}

// Same, 4-quadrant source (k-half x n-half), K=1024
__global__ __launch_bounds__(256) void k_transG(const float* __restrict__ s00,
                                                const float* __restrict__ s10,
                                                const float* __restrict__ s01,
                                                const float* __restrict__ s11,
                                                short* __restrict__ Fhi,
                                                short* __restrict__ Flo) {
    __shared__ float st[32][33];
    const int K = 2 * DD;
    int tx = threadIdx.x & 31, ty = threadIdx.x >> 5;
    int k0 = blockIdx.x * 32, n0 = blockIdx.y * 32;
    const float* sk0 = (n0 < DD) ? s00 : s01;
    const float* sk1 = (n0 < DD) ? s10 : s11;
    #pragma unroll
    for (int i = 0; i < 4; i++) {
        int k = k0 + ty + i * 8;
        const float* s = (k < DD) ? sk0 : sk1;
        st[ty + i * 8][tx] = s[(size_t)(k & (DD - 1)) * DD + ((n0 + tx) & (DD - 1))];
    }
    __syncthreads();
    #pragma unroll
    for (int i = 0; i < 4; i++) {
        int n = n0 + ty + i * 8, k = k0 + tx;
        float v = st[tx][ty + i * 8];
        unsigned short hs, ls;
        split2(v, hs, ls);
        size_t a = ((size_t)(n >> 4) * (K >> 3) + (k >> 3)) * 128 + ((n & 15) << 3) + (k & 7);
        Fhi[a] = (short)hs;
        Flo[a] = (short)ls;
    }
}

// All-edge gather: 128 column-threads x 2 edge halves, float4 loads,
// u32-staged idx, 8-wide + 4-wide remainder; nt stores for Gbig/abuf.
__global__ __launch_bounds__(256) void k_gather_all(const float* __restrict__ h,
                                                    const int* __restrict__ cnt2,
                                                    const unsigned short* __restrict__ idx,
                                                    const float* __restrict__ bp,
                                                    short* __restrict__ Gbhi,
                                                    short* __restrict__ Gblo,
                                                    float* __restrict__ abuf) {
    __shared__ unsigned short sidx[NEDGE * MAXE];
    __shared__ int scnt[NEDGE];
    int n = blockIdx.x, t = threadIdx.x;

    if (t < NEDGE) scnt[t] = cnt2[n * NEDGE + t];
    for (int j = t; j < NEDGE * MAXE / 2; j += 256)
        ((unsigned*)sidx)[j] = ((const unsigned*)(idx + (size_t)n * NEDGE * MAXE))[j];
    __syncthreads();

    const int th = t & 127;        // column group: cols 4*th .. 4*th+3
    const int eg = t >> 7;         // edge half: edges eg*4 .. eg*4+3
    size_t wbase = ((size_t)(n >> 4) * 512) * 128 + ((n & 15) << 3) + ((th & 1) << 2);

    #pragma unroll 1
    for (int ee = 0; ee < 4; ee++) {
        int e = eg * 4 + ee;
        int raw = scnt[e];
        int m = raw > MAXE ? MAXE : raw;
        const unsigned short* row = &sidx[e * MAXE];
        floatx4 a = (floatx4){0.f, 0.f, 0.f, 0.f};
        int i = 0;
        for (; i + 8 <= m; i += 8) {
            #pragma unroll
            for (int j = 0; j < 8; j++)
                a += *(const floatx4*)(h + (size_t)row[i + j] * DD + 4 * th);
        }
        if (i + 4 <= m) {
            #pragma unroll
            for (int j = 0; j < 4; j++)
                a += *(const floatx4*)(h + (size_t)row[i + j] * DD + 4 * th);
            i += 4;
        }
        for (; i < m; i++)
            a += *(const floatx4*)(h + (size_t)row[i] * DD + 4 * th);

        unsigned short hs[4], ls[4];
        #pragma unroll
        for (int j = 0; j < 4; j++) split2(a[j], hs[j], ls[j]);
        unsigned long long hp = (unsigned long long)hs[0] | ((unsigned long long)hs[1] << 16)
                              | ((unsigned long long)hs[2] << 32) | ((unsigned long long)hs[3] << 48);
        unsigned long long lp = (unsigned long long)ls[0] | ((unsigned long long)ls[1] << 16)
                              | ((unsigned long long)ls[2] << 32) | ((unsigned long long)ls[3] << 48);
        size_t addr = wbase + (size_t)(e * 64 + (th >> 1)) * 128;
        __builtin_nontemporal_store(hp, (unsigned long long*)(Gbhi + addr));
        __builtin_nontemporal_store(lp, (unsigned long long*)(Gblo + addr));
    }

    if (eg == 0) {
        floatx4 s = (floatx4){0.f, 0.f, 0.f, 0.f};
        #pragma unroll
        for (int e = 0; e < NEDGE; e++)
            s += (float)scnt[e] * *(const floatx4*)(bp + e * DD + 4 * th);
        __builtin_nontemporal_store(s, (floatx4*)(abuf + (size_t)n * DD + 4 * th));
    }
}

// Split-bf16 MFMA GEMM on FO operands: C = (Ahi+Alo)@(Bhi+Blo)^T (3 products), fp32 acc.
// Block 64(M)x32(N), 4 waves (2m x 2n), wave 32x16. BK=64, LDS dbuf (48 KB),
// 1 barrier/iter, VGPR staging (nt loads for prop A). XCD-banded swizzle.
// MODE 0 (prop): K=4096, A=Gbig. v = acc + abuf[o]; Ga = split(v).
// MODE 1 (zr):   K=1024 (A seg: Ga|HB), N=1024. col<512: zbuf=sigmoid(v+b0);
//                else RH = split(sigmoid(v+b1)*h).
// MODE 2 (fin):  K=1024 (A seg: Ga|RH). hn=(1-z)h+z*tanh(v+b0); h, HB, outF.
template<int MODE>
__global__ __launch_bounds__(256, 3) void k_gemm6(
    const short* __restrict__ A0hi, const short* __restrict__ A0lo,
    const short* __restrict__ A1hi, const short* __restrict__ A1lo,
    const short* __restrict__ Bhi,  const short* __restrict__ Blo, int K,
    const float* __restrict__ bias0, const float* __restrict__ bias1,
    float* __restrict__ zbuf,
    float* __restrict__ h,
    short* __restrict__ Ohi, short* __restrict__ Olo,
    float* __restrict__ outF) {

    __shared__ short S[2][24][512];   // 2 bufs x 24 slots x 1KB = 48 KB

    const int tid = threadIdx.x;
    const int lane = tid & 63;
    const int wave = tid >> 6;
    const int wm = wave >> 1;          // m-half (32 rows)
    const int wn = wave & 1;           // n-tile (16 cols)
    const int quad = lane >> 4;
    const int l16 = lane & 15;

    // XCD-banded swizzle (gridDim.y == 32 for all grids here)
    const int pbid = blockIdx.y * gridDim.x + blockIdx.x;
    const int bx = pbid >> 5;
    const int by = (pbid & 7) * 4 + ((pbid >> 3) & 3);
    const int blockM = by * 64;
    const int blockN = bx * 32;
    const int mt0 = blockM >> 4, nt0 = blockN >> 4;
    const int KCB = K >> 3;            // B kchunk stride

    floatx4 acc[2];
    acc[0] = (floatx4){0.f, 0.f, 0.f, 0.f};
    acc[1] = (floatx4){0.f, 0.f, 0.f, 0.f};

    // slots: 0..7 A-hi (mt=u>>1, ks=u&1); 8..15 A-lo; 16..23 B (pl=u>>2, ks=(u>>1)&1, nt=u&1)
    auto gaddr = [&](int k0, int s) -> const short* {
        if (s < 16) {
            int pl = s >> 3;           // 0 = hi, 1 = lo
            int u = s & 7;
            int mt = u >> 1, ks = u & 1;
            if (MODE == 0) {
                const short* base = pl ? A0lo : A0hi;
                return base + ((size_t)(mt0 + mt) * 512 + (k0 >> 3) + ks * 4) * 128;
            } else {
                int seg = k0 >> 9;
                const short* base = seg ? (pl ? A1lo : A1hi) : (pl ? A0lo : A0hi);
                return base + ((size_t)(mt0 + mt) * 64 + (((k0 & 511) >> 3) + ks * 4)) * 128;
            }
        } else {
            int u = s - 16, pl = u >> 2, ks = (u >> 1) & 1, nt = u & 1;
            const short* base = pl ? Blo : Bhi;
            return base + ((size_t)(nt0 + nt) * KCB + (k0 >> 3) + ks * 4) * 128;
        }
    };

    // prop A is re-read only x16 while B is re-read x32: keep A out of L2 (nt)
    auto ldslot = [&](int k0, int s) -> short8 {
        const short8* g = (const short8*)(gaddr(k0, s) + lane * 8);
        if (MODE == 0 && s < 16) return __builtin_nontemporal_load(g);
        return *g;
    };

    short8 rg[6];
    #pragma unroll
    for (int j = 0; j < 6; j++)
        rg[j] = ldslot(0, j * 4 + wave);
    #pragma unroll
    for (int j = 0; j < 6; j++)
        *(short8*)&S[0][j * 4 + wave][lane * 8] = rg[j];

    for (int k0 = 0; k0 < K; k0 += 64) {
        const int buf = (k0 >> 6) & 1;
        const bool more = (k0 + 64 < K);
        if (more) {
            #pragma unroll
            for (int j = 0; j < 6; j++)
                rg[j] = ldslot(k0 + 64, j * 4 + wave);
        }
        __syncthreads();

        #pragma unroll
        for (int ks = 0; ks < 2; ks++) {
            short8 ah[2], al[2], bh, bl;
            #pragma unroll
            for (int mi = 0; mi < 2; mi++) {
                ah[mi] = *(const short8*)&S[buf][(wm * 2 + mi) * 2 + ks][lane * 8];
                al[mi] = *(const short8*)&S[buf][8 + (wm * 2 + mi) * 2 + ks][lane * 8];
            }
            bh = *(const short8*)&S[buf][16 + ks * 2 + wn][lane * 8];
            bl = *(const short8*)&S[buf][20 + ks * 2 + wn][lane * 8];
            #pragma unroll
            for (int mi = 0; mi < 2; mi++) {
                acc[mi] = __builtin_amdgcn_mfma_f32_16x16x32_bf16(ah[mi], bh, acc[mi], 0, 0, 0);
                acc[mi] = __builtin_amdgcn_mfma_f32_16x16x32_bf16(ah[mi], bl, acc[mi], 0, 0, 0);
                acc[mi] = __builtin_amdgcn_mfma_f32_16x16x32_bf16(al[mi], bh, acc[mi], 0, 0, 0);
            }
        }

        if (more) {
            #pragma unroll
            for (int j = 0; j < 6; j++)
                *(short8*)&S[buf ^ 1][j * 4 + wave][lane * 8] = rg[j];
        }
    }

    // C/D layout (m89-verified): elem r -> row = quad*4+r, col = l16
    #pragma unroll
    for (int mi = 0; mi < 2; mi++) {
        int gcol = blockN + wn * 16 + l16;
        #pragma unroll
        for (int r = 0; r < 4; r++) {
            int grow = blockM + wm * 32 + mi * 16 + quad * 4 + r;
            float v = acc[mi][r];
            if (MODE == 0) {
                size_t o = (size_t)grow * DD + gcol;
                fo_write(Ohi, Olo, grow, gcol, v + zbuf[o]);
            } else if (MODE == 1) {
                if (gcol < DD) {
                    size_t o = (size_t)grow * DD + gcol;
                    zbuf[o] = 1.f / (1.f + __expf(-(v + bias0[gcol])));
                } else {
                    int c = gcol - DD;
                    size_t o = (size_t)grow * DD + c;
                    float rr = 1.f / (1.f + __expf(-(v + bias1[c])));
                    fo_write(Ohi, Olo, grow, c, rr * h[o]);
                }
            } else {
                size_t o = (size_t)grow * DD + gcol;
                float zv = zbuf[o];
                float hv = h[o];
                float hn = (1.f - zv) * hv + zv * tanhf(v + bias0[gcol]);
                h[o] = hn;
                fo_write(Ohi, Olo, grow, gcol, hn);
                outF[o] = hn;
            }
        }
    }
}

extern "C" void kernel_launch(void* const* d_in, const int* in_sizes, int n_in,
                              void* d_out, int out_size, void* d_ws, size_t ws_size,
                              hipStream_t stream) {
    const float* adj = (const float*)d_in[0];
    const float* ann = (const float*)d_in[1];
    const float* Wp  = (const float*)d_in[2];
    const float* bp  = (const float*)d_in[3];
    const float* Wz  = (const float*)d_in[4];
    const float* Uz  = (const float*)d_in[5];
    const float* bz  = (const float*)d_in[6];
    const float* Wr  = (const float*)d_in[7];
    const float* Ur  = (const float*)d_in[8];
    const float* br  = (const float*)d_in[9];
    const float* Wh  = (const float*)d_in[10];
    const float* Uh  = (const float*)d_in[11];
    const float* bh  = (const float*)d_in[12];

    // workspace carve (~69 MB; ws ~512 MB per round-4 fill counters)
    char* p = (char*)d_ws;
    float* h     = (float*)p; p += (size_t)NNODE * DD * 4;          // 4 MB
    float* abuf  = (float*)p; p += (size_t)NNODE * DD * 4;          // 4 MB deg-bias -> z
    short* Gbhi  = (short*)p; p += (size_t)NNODE * KP * 2;          // 16 MB (FO K=4096)
    short* Gblo  = (short*)p; p += (size_t)NNODE * KP * 2;          // 16 MB
    short* Gahi  = (short*)p; p += (size_t)NNODE * DD * 2;          // 2 MB (FO K=512)
    short* Galo  = (short*)p; p += (size_t)NNODE * DD * 2;
    short* HBhi  = (short*)p; p += (size_t)NNODE * DD * 2;
    short* HBlo  = (short*)p; p += (size_t)NNODE * DD * 2;
    short* RHhi  = (short*)p; p += (size_t)NNODE * DD * 2;
    short* RHlo  = (short*)p; p += (size_t)NNODE * DD * 2;
    short* WpThi = (short*)p; p += (size_t)DD * KP * 2;             // 4 MB (FO N=512,K=4096)
    short* WpTlo = (short*)p; p += (size_t)DD * KP * 2;
    short* ZRhi  = (short*)p; p += (size_t)(2 * DD) * (2 * DD) * 2; // 2 MB (FO N=1024,K=1024)
    short* ZRlo  = (short*)p; p += (size_t)(2 * DD) * (2 * DD) * 2;
    short* HThi  = (short*)p; p += (size_t)DD * (2 * DD) * 2;       // 1 MB (FO N=512,K=1024)
    short* HTlo  = (short*)p; p += (size_t)DD * (2 * DD) * 2;
    unsigned short* idx = (unsigned short*)p;
    p += (size_t)NNODE * NEDGE * MAXE * 2;                          // 3 MB
    int* cnt2 = (int*)p; p += (size_t)NNODE * NEDGE * 4;

    float* outF = (float*)d_out;

    k_init<<<NNODE, 256, 0, stream>>>(ann, h, HBhi, HBlo, cnt2);
    k_build<<<NNODE, 256, 0, stream>>>(adj, cnt2, idx);
    k_transP<<<dim3(KP / 32, DD / 32), 256, 0, stream>>>(Wp, WpThi, WpTlo, KP);
    k_transG<<<dim3(32, 32), 256, 0, stream>>>(Wz, Uz, Wr, Ur, ZRhi, ZRlo);
    k_transG<<<dim3(32, 16), 256, 0, stream>>>(Wh, Uh, Wh, Uh, HThi, HTlo);

    dim3 gP(DD / 32, NNODE / 64);        // (16, 32) = 512 blocks
    dim3 gZ(2 * DD / 32, NNODE / 64);    // (32, 32) = 1024 blocks
    for (int s = 0; s < NSTEPS; s++) {
        k_gather_all<<<NNODE, 256, 0, stream>>>(h, cnt2, idx, bp, Gbhi, Gblo, abuf);
        // a = Gbig @ WpT + deg-bias -> Ga (FO hi/lo)
        k_gemm6<0><<<gP, 256, 0, stream>>>(Gbhi, Gblo, nullptr, nullptr,
                                           WpThi, WpTlo, KP, nullptr, nullptr,
                                           abuf, nullptr, Gahi, Galo, nullptr);
        // [z|r]: z -> abuf (fp32), RH = split(sigmoid(.)*h)
        k_gemm6<1><<<gZ, 256, 0, stream>>>(Gahi, Galo, HBhi, HBlo,
                                           ZRhi, ZRlo, 2 * DD, bz, br,
                                           abuf, h, RHhi, RHlo, nullptr);
        // h' = (1-z)h + z*tanh([a|rh]@[Wh;Uh]+bh) -> h, HB, d_out
        k_gemm6<2><<<gP, 256, 0, stream>>>(Gahi, Galo, RHhi, RHlo,
                                           HThi, HTlo, 2 * DD, bh, nullptr,
                                           abuf, h, HBhi, HBlo, outF);
    }
}

// Round 13
// 1053.746 us; speedup vs baseline: 1.5220x; 1.4562x over previous
//
#include <hip/hip_runtime.h>

typedef __attribute__((ext_vector_type(8))) short short8;
typedef __attribute__((ext_vector_type(4))) float floatx4;

#define NSTEPS 5
#define DD 512
#define ANN 256
#define NNODE 2048
#define NEDGE 8                 // 2*E
#define NCOLS (NNODE * NEDGE)   // 16384
#define MAXE 96                 // nnz per (node,edge-type): mean 30.7, sd 5.5
#define KP (NEDGE * DD)         // 4096

// Fragment-ordered (FO) layout for [M][K] bf16:
// addr(row,k) = ((row>>4)*(K>>3) + (k>>3))*128 + ((row&15)<<3) + (k&7)
// One slot = 16 rows x 32 k = 1KB, lane l's 16B at slot_base + l*16.

typedef __attribute__((address_space(3))) unsigned lds_u32;
typedef const __attribute__((address_space(1))) unsigned g_u32;
__device__ __forceinline__ void gload16(const short* g, short* l) {
    __builtin_amdgcn_global_load_lds((g_u32*)g, (lds_u32*)l, 16, 0, 0);
}

__device__ inline float bf2f(unsigned short s) {
    unsigned u = ((unsigned)s) << 16;
    float f; __builtin_memcpy(&f, &u, 4);
    return f;
}
__device__ inline unsigned short f2bf(float f) {   // round-to-nearest-even
    unsigned u; __builtin_memcpy(&u, &f, 4);
    u += 0x7fffu + ((u >> 16) & 1u);
    return (unsigned short)(u >> 16);
}
__device__ inline void split2(float x, unsigned short& hi, unsigned short& lo) {
    hi = f2bf(x);
    lo = f2bf(x - bf2f(hi));
}
// split-write one element into FO hi/lo planes (K=512)
__device__ inline void fo_write(short* __restrict__ Fhi, short* __restrict__ Flo,
                                int row, int col, float v) {
    unsigned short hs, ls;
    split2(v, hs, ls);
    size_t a = ((size_t)(row >> 4) * 64 + (col >> 3)) * 128 + ((row & 15) << 3) + (col & 7);
    Fhi[a] = (short)hs;
    Flo[a] = (short)ls;
}
// split-write a pair of adjacent cols (c even) as one u32 per plane
__device__ inline void fo_write2(short* __restrict__ Fhi, short* __restrict__ Flo,
                                 int row, int c, float v0, float v1) {
    unsigned short h0, l0, h1, l1;
    split2(v0, h0, l0);
    split2(v1, h1, l1);
    size_t a = ((size_t)(row >> 4) * 64 + (c >> 3)) * 128 + ((row & 15) << 3) + (c & 7);
    *(unsigned*)(Fhi + a) = (unsigned)h0 | ((unsigned)h1 << 16);
    *(unsigned*)(Flo + a) = (unsigned)l0 | ((unsigned)l1 << 16);
}

// h = [ann | 0] fp32; HB (FO, K=512) = split(h); cnt2 = 0
__global__ __launch_bounds__(256) void k_init(const float* __restrict__ ann,
                                              float* __restrict__ h,
                                              short* __restrict__ HBhi,
                                              short* __restrict__ HBlo,
                                              int* __restrict__ cnt2) {
    int n = blockIdx.x, t = threadIdx.x;
    int c = 2 * t;
    float v0 = 0.f, v1 = 0.f;
    if (c < ANN) {
        v0 = ann[(size_t)n * ANN + c];
        v1 = ann[(size_t)n * ANN + c + 1];
    }
    h[(size_t)n * DD + c]     = v0;
    h[(size_t)n * DD + c + 1] = v1;
    fo_write2(HBhi, HBlo, n, c, v0, v1);
    if (t < NEDGE) cnt2[n * NEDGE + t] = 0;
}

// fp32 0/1 adjacency -> per-(row, edge-type) source-node index lists
__global__ __launch_bounds__(256) void k_build(const float* __restrict__ adj,
                                               int* __restrict__ cnt2,
                                               unsigned short* __restrict__ idx) {
    int n = blockIdx.x;
    const float* row = adj + (size_t)n * NCOLS;
    for (int j8 = threadIdx.x; j8 < NCOLS / 8; j8 += 256) {
        floatx4 a = *(const floatx4*)(row + j8 * 8);
        floatx4 b = *(const floatx4*)(row + j8 * 8 + 4);
        unsigned nz = 0;
        #pragma unroll
        for (int i = 0; i < 4; i++) {
            if (a[i] != 0.f) nz |= 1u << i;
            if (b[i] != 0.f) nz |= 1u << (4 + i);
        }
        while (nz) {
            int i = __builtin_ctz(nz);
            nz &= nz - 1;
            int j = j8 * 8 + i;
            int e = j >> 11;
            int m = j & (NNODE - 1);
            int p = atomicAdd(&cnt2[n * NEDGE + e], 1);
            if (p < MAXE) idx[((size_t)n * NEDGE + e) * MAXE + p] = (unsigned short)m;
        }
    }
}

// Transpose+split weights into FO (hi & lo), contiguous-K source [K][512]
__global__ __launch_bounds__(256) void k_transP(const float* __restrict__ W,
                                                short* __restrict__ Fhi,
                                                short* __restrict__ Flo, int K) {
    __shared__ float st[32][33];
    int tx = threadIdx.x & 31, ty = threadIdx.x >> 5;
    int k0 = blockIdx.x * 32, n0 = blockIdx.y * 32;
    #pragma unroll
    for (int i = 0; i < 4; i++)
        st[ty + i * 8][tx] = W[(size_t)(k0 + ty + i * 8) * DD + n0 + tx];
    __syncthreads();
    #pragma unroll
    for (int i = 0; i < 4; i++) {
        int n = n0 + ty + i * 8, k = k0 + tx;
        float v = st[tx][ty + i * 8];
        unsigned short hs, ls;
        split2(v, hs, ls);
        size_t a = ((size_t)(n >> 4) * (K >> 3) + (k >> 3)) * 128 + ((n & 15) << 3) + (k & 7);
        Fhi[a] = (short)hs;
        Flo[a] = (short)ls;
    }
}

// Same, 4-quadrant source (k-half x n-half), K=1024
__global__ __launch_bounds__(256) void k_transG(const float* __restrict__ s00,
                                                const float* __restrict__ s10,
                                                const float* __restrict__ s01,
                                                const float* __restrict__ s11,
                                                short* __restrict__ Fhi,
                                                short* __restrict__ Flo) {
    __shared__ float st[32][33];
    const int K = 2 * DD;
    int tx = threadIdx.x & 31, ty = threadIdx.x >> 5;
    int k0 = blockIdx.x * 32, n0 = blockIdx.y * 32;
    const float* sk0 = (n0 < DD) ? s00 : s01;
    const float* sk1 = (n0 < DD) ? s10 : s11;
    #pragma unroll
    for (int i = 0; i < 4; i++) {
        int k = k0 + ty + i * 8;
        const float* s = (k < DD) ? sk0 : sk1;
        st[ty + i * 8][tx] = s[(size_t)(k & (DD - 1)) * DD + ((n0 + tx) & (DD - 1))];
    }
    __syncthreads();
    #pragma unroll
    for (int i = 0; i < 4; i++) {
        int n = n0 + ty + i * 8, k = k0 + tx;
        float v = st[tx][ty + i * 8];
        unsigned short hs, ls;
        split2(v, hs, ls);
        size_t a = ((size_t)(n >> 4) * (K >> 3) + (k >> 3)) * 128 + ((n & 15) << 3) + (k & 7);
        Fhi[a] = (short)hs;
        Flo[a] = (short)ls;
    }
}

// All-edge gather: 128 column-threads x 2 edge halves, float4 loads, MLP 16
// (dual accumulators); nt stores for Gbig/abuf.
__global__ __launch_bounds__(256) void k_gather_all(const float* __restrict__ h,
                                                    const int* __restrict__ cnt2,
                                                    const unsigned short* __restrict__ idx,
                                                    const float* __restrict__ bp,
                                                    short* __restrict__ Gbhi,
                                                    short* __restrict__ Gblo,
                                                    float* __restrict__ abuf) {
    __shared__ unsigned short sidx[NEDGE * MAXE];
    __shared__ int scnt[NEDGE];
    int n = blockIdx.x, t = threadIdx.x;

    if (t < NEDGE) scnt[t] = cnt2[n * NEDGE + t];
    for (int j = t; j < NEDGE * MAXE / 2; j += 256)
        ((unsigned*)sidx)[j] = ((const unsigned*)(idx + (size_t)n * NEDGE * MAXE))[j];
    __syncthreads();

    const int th = t & 127;        // column group: cols 4*th .. 4*th+3
    const int eg = t >> 7;         // edge half: edges eg*4 .. eg*4+3
    size_t wbase = ((size_t)(n >> 4) * 512) * 128 + ((n & 15) << 3) + ((th & 1) << 2);

    #pragma unroll 1
    for (int ee = 0; ee < 4; ee++) {
        int e = eg * 4 + ee;
        int raw = scnt[e];
        int m = raw > MAXE ? MAXE : raw;
        const unsigned short* row = &sidx[e * MAXE];
        floatx4 a0 = (floatx4){0.f, 0.f, 0.f, 0.f};
        floatx4 a1 = (floatx4){0.f, 0.f, 0.f, 0.f};
        int i = 0;
        for (; i + 16 <= m; i += 16) {
            #pragma unroll
            for (int j = 0; j < 8; j++) {
                a0 += *(const floatx4*)(h + (size_t)row[i + j] * DD + 4 * th);
                a1 += *(const floatx4*)(h + (size_t)row[i + 8 + j] * DD + 4 * th);
            }
        }
        if (i + 8 <= m) {
            #pragma unroll
            for (int j = 0; j < 8; j++)
                a0 += *(const floatx4*)(h + (size_t)row[i + j] * DD + 4 * th);
            i += 8;
        }
        if (i + 4 <= m) {
            #pragma unroll
            for (int j = 0; j < 4; j++)
                a1 += *(const floatx4*)(h + (size_t)row[i + j] * DD + 4 * th);
            i += 4;
        }
        for (; i < m; i++)
            a0 += *(const floatx4*)(h + (size_t)row[i] * DD + 4 * th);
        floatx4 a = a0 + a1;

        unsigned short hs[4], ls[4];
        #pragma unroll
        for (int j = 0; j < 4; j++) split2(a[j], hs[j], ls[j]);
        unsigned long long hp = (unsigned long long)hs[0] | ((unsigned long long)hs[1] << 16)
                              | ((unsigned long long)hs[2] << 32) | ((unsigned long long)hs[3] << 48);
        unsigned long long lp = (unsigned long long)ls[0] | ((unsigned long long)ls[1] << 16)
                              | ((unsigned long long)ls[2] << 32) | ((unsigned long long)ls[3] << 48);
        size_t addr = wbase + (size_t)(e * 64 + (th >> 1)) * 128;
        __builtin_nontemporal_store(hp, (unsigned long long*)(Gbhi + addr));
        __builtin_nontemporal_store(lp, (unsigned long long*)(Gblo + addr));
    }

    if (eg == 0) {
        floatx4 s = (floatx4){0.f, 0.f, 0.f, 0.f};
        #pragma unroll
        for (int e = 0; e < NEDGE; e++)
            s += (float)scnt[e] * *(const floatx4*)(bp + e * DD + 4 * th);
        __builtin_nontemporal_store(s, (floatx4*)(abuf + (size_t)n * DD + 4 * th));
    }
}

// Split-bf16 MFMA GEMM on FO operands (m97 structure: single 24 KB LDS buffer,
// global_load_lds(16B) staging, 2 barriers/iter). Block 64(M)x32(N), 4 waves
// (2m x 2n), wave 32x16. C = (Ahi+Alo)@(Bhi+Blo)^T (3 products), fp32 acc.
// 1D grids of 1024 blocks (4/CU):
// MODE 0 (prop): K split 2 (kh): block K=2048 of Gbig@WpT; P[kh][o] = acc.
// MODE 1 (zr):   K=1024 (A seg: Ga|HB), N=1024. col<512: zbuf=sigmoid(v+b0);
//                else RH = split(sigmoid(v+b1)*h).
// MODE 2 (fin):  seg split (kh): kh=0: Ga@Wh (K=512), kh=1: RH@Uh; P[kh][o]=acc.
template<int MODE>
__global__ __launch_bounds__(256, 4) void k_gemm8(
    const short* __restrict__ A0hi, const short* __restrict__ A0lo,
    const short* __restrict__ A1hi, const short* __restrict__ A1lo,
    const short* __restrict__ Bhi,  const short* __restrict__ Blo,
    const float* __restrict__ bias0, const float* __restrict__ bias1,
    float* __restrict__ zbuf,
    float* __restrict__ h,
    short* __restrict__ Ohi, short* __restrict__ Olo,
    float* __restrict__ P0, float* __restrict__ P1) {

    __shared__ short S[24][512];   // 24 slots x 1KB = 24 KB (single buffer)

    const int tid = threadIdx.x;
    const int lane = tid & 63;
    const int wave = tid >> 6;
    const int wm = wave >> 1;          // m-half (32 rows)
    const int wn = wave & 1;           // n-tile (16 cols)
    const int quad = lane >> 4;
    const int l16 = lane & 15;

    // 1D grid decode (XCD-banded: dispatch round-robin pbid%8 assumed)
    const int pbid = blockIdx.x;
    const int x = pbid & 7;
    const int j = pbid >> 3;           // 0..127
    const int mband = x * 4 + (j & 3); // 0..31
    int kh, bx;
    if (MODE == 1) { kh = 0; bx = j >> 2; }            // bx 0..31
    else           { kh = (j >> 2) & 1; bx = j >> 3; } // bx 0..15
    const int blockM = mband * 64;
    const int blockN = bx * 32;
    const int mt0 = blockM >> 4, nt0 = blockN >> 4;
    const int KCB = (MODE == 0) ? 512 : 128;           // B row stride (kchunks)
    const int bko = (MODE == 0) ? kh * 256 : (MODE == 2 ? kh * 64 : 0);
    const int Kloc = (MODE == 0) ? 2048 : (MODE == 1 ? 1024 : 512);

    const short* Ahi_s = (MODE == 2 && kh) ? A1hi : A0hi;
    const short* Alo_s = (MODE == 2 && kh) ? A1lo : A0lo;

    floatx4 acc[2];
    acc[0] = (floatx4){0.f, 0.f, 0.f, 0.f};
    acc[1] = (floatx4){0.f, 0.f, 0.f, 0.f};

    // slots: 0..7 A-hi (mt=u>>1, ks=u&1); 8..15 A-lo; 16..23 B (pl=u>>2, ks=(u>>1)&1, nt=u&1)
    auto gaddr = [&](int k0, int s) -> const short* {
        if (s < 16) {
            int pl = s >> 3, u = s & 7;
            int mt = u >> 1, ks = u & 1;
            const short* base;
            int kc, stride;
            if (MODE == 0) {
                base = pl ? A0lo : A0hi;
                kc = kh * 256 + (k0 >> 3) + ks * 4;
                stride = 512;
            } else if (MODE == 1) {
                int seg = k0 >> 9;
                base = seg ? (pl ? A1lo : A1hi) : (pl ? A0lo : A0hi);
                kc = ((k0 & 511) >> 3) + ks * 4;
                stride = 64;
            } else {
                base = pl ? Alo_s : Ahi_s;
                kc = (k0 >> 3) + ks * 4;
                stride = 64;
            }
            return base + ((size_t)(mt0 + mt) * stride + kc) * 128;
        } else {
            int u = s - 16, pl = u >> 2, ks = (u >> 1) & 1, nt = u & 1;
            const short* base = pl ? Blo : Bhi;
            return base + ((size_t)(nt0 + nt) * KCB + bko + (k0 >> 3) + ks * 4) * 128;
        }
    };

    for (int k0 = 0; k0 < Kloc; k0 += 64) {
        // stage: each wave DMAs 6 slots (wave-uniform LDS base + lane*16)
        #pragma unroll
        for (int jj = 0; jj < 6; jj++) {
            int s = jj * 4 + wave;
            gload16(gaddr(k0, s) + lane * 8, &S[s][lane * 8]);
        }
        __syncthreads();   // drains DMA (vmcnt) + ensures all waves staged

        #pragma unroll
        for (int ks = 0; ks < 2; ks++) {
            short8 ah[2], al[2], bh, bl;
            #pragma unroll
            for (int mi = 0; mi < 2; mi++) {
                ah[mi] = *(const short8*)&S[(wm * 2 + mi) * 2 + ks][lane * 8];
                al[mi] = *(const short8*)&S[8 + (wm * 2 + mi) * 2 + ks][lane * 8];
            }
            bh = *(const short8*)&S[16 + ks * 2 + wn][lane * 8];
            bl = *(const short8*)&S[20 + ks * 2 + wn][lane * 8];
            #pragma unroll
            for (int mi = 0; mi < 2; mi++) {
                acc[mi] = __builtin_amdgcn_mfma_f32_16x16x32_bf16(ah[mi], bh, acc[mi], 0, 0, 0);
                acc[mi] = __builtin_amdgcn_mfma_f32_16x16x32_bf16(ah[mi], bl, acc[mi], 0, 0, 0);
                acc[mi] = __builtin_amdgcn_mfma_f32_16x16x32_bf16(al[mi], bh, acc[mi], 0, 0, 0);
            }
        }
        __syncthreads();   // all reads done before next stage overwrites
    }

    // C/D layout (m89-verified): elem r -> row = quad*4+r, col = l16
    float* P = kh ? P1 : P0;
    #pragma unroll
    for (int mi = 0; mi < 2; mi++) {
        int gcol = blockN + wn * 16 + l16;
        #pragma unroll
        for (int r = 0; r < 4; r++) {
            int grow = blockM + wm * 32 + mi * 16 + quad * 4 + r;
            float v = acc[mi][r];
            if (MODE == 0 || MODE == 2) {
                P[(size_t)grow * DD + gcol] = v;
            } else {
                if (gcol < DD) {
                    size_t o = (size_t)grow * DD + gcol;
                    zbuf[o] = 1.f / (1.f + __expf(-(v + bias0[gcol])));
                } else {
                    int c = gcol - DD;
                    size_t o = (size_t)grow * DD + c;
                    float rr = 1.f / (1.f + __expf(-(v + bias1[c])));
                    fo_write(Ohi, Olo, grow, c, rr * h[o]);
                }
            }
        }
    }
}

// Ga = split(P0 + P1 + abuf)   (prop combine)
__global__ __launch_bounds__(256) void k_combP(const float* __restrict__ P0,
                                               const float* __restrict__ P1,
                                               const float* __restrict__ abuf,
                                               short* __restrict__ Gahi,
                                               short* __restrict__ Galo) {
    int n = blockIdx.x, t = threadIdx.x;
    size_t o = (size_t)n * DD + 2 * t;
    float v0 = P0[o] + P1[o] + abuf[o];
    float v1 = P0[o + 1] + P1[o + 1] + abuf[o + 1];
    fo_write2(Gahi, Galo, n, 2 * t, v0, v1);
}

// GRU combine: hn = (1-z)h + z*tanh(P0+P1+bh) -> h, HB (FO), outF
__global__ __launch_bounds__(256) void k_combF(const float* __restrict__ P0,
                                               const float* __restrict__ P1,
                                               const float* __restrict__ bh,
                                               const float* __restrict__ zbuf,
                                               float* __restrict__ h,
                                               short* __restrict__ HBhi,
                                               short* __restrict__ HBlo,
                                               float* __restrict__ outF) {
    int n = blockIdx.x, t = threadIdx.x;
    int c = 2 * t;
    size_t o = (size_t)n * DD + c;
    float hn0, hn1;
    {
        float v = P0[o] + P1[o] + bh[c];
        hn0 = (1.f - zbuf[o]) * h[o] + zbuf[o] * tanhf(v);
    }
    {
        float v = P0[o + 1] + P1[o + 1] + bh[c + 1];
        hn1 = (1.f - zbuf[o + 1]) * h[o + 1] + zbuf[o + 1] * tanhf(v);
    }
    h[o] = hn0;
    h[o + 1] = hn1;
    fo_write2(HBhi, HBlo, n, c, hn0, hn1);
    outF[o] = hn0;
    outF[o + 1] = hn1;
}

extern "C" void kernel_launch(void* const* d_in, const int* in_sizes, int n_in,
                              void* d_out, int out_size, void* d_ws, size_t ws_size,
                              hipStream_t stream) {
    const float* adj = (const float*)d_in[0];
    const float* ann = (const float*)d_in[1];
    const float* Wp  = (const float*)d_in[2];
    const float* bp  = (const float*)d_in[3];
    const float* Wz  = (const float*)d_in[4];
    const float* Uz  = (const float*)d_in[5];
    const float* bz  = (const float*)d_in[6];
    const float* Wr  = (const float*)d_in[7];
    const float* Ur  = (const float*)d_in[8];
    const float* br  = (const float*)d_in[9];
    const float* Wh  = (const float*)d_in[10];
    const float* Uh  = (const float*)d_in[11];
    const float* bh  = (const float*)d_in[12];

    // workspace carve (~77 MB; ws ~512 MB per round-4 fill counters)
    char* p = (char*)d_ws;
    float* h     = (float*)p; p += (size_t)NNODE * DD * 4;          // 4 MB
    float* abuf  = (float*)p; p += (size_t)NNODE * DD * 4;          // 4 MB deg-bias -> z
    float* P0    = (float*)p; p += (size_t)NNODE * DD * 4;          // 4 MB split-K partial
    float* P1    = (float*)p; p += (size_t)NNODE * DD * 4;          // 4 MB
    short* Gbhi  = (short*)p; p += (size_t)NNODE * KP * 2;          // 16 MB (FO K=4096)
    short* Gblo  = (short*)p; p += (size_t)NNODE * KP * 2;          // 16 MB
    short* Gahi  = (short*)p; p += (size_t)NNODE * DD * 2;          // 2 MB (FO K=512)
    short* Galo  = (short*)p; p += (size_t)NNODE * DD * 2;
    short* HBhi  = (short*)p; p += (size_t)NNODE * DD * 2;
    short* HBlo  = (short*)p; p += (size_t)NNODE * DD * 2;
    short* RHhi  = (short*)p; p += (size_t)NNODE * DD * 2;
    short* RHlo  = (short*)p; p += (size_t)NNODE * DD * 2;
    short* WpThi = (short*)p; p += (size_t)DD * KP * 2;             // 4 MB (FO N=512,K=4096)
    short* WpTlo = (short*)p; p += (size_t)DD * KP * 2;
    short* ZRhi  = (short*)p; p += (size_t)(2 * DD) * (2 * DD) * 2; // 2 MB (FO N=1024,K=1024)
    short* ZRlo  = (short*)p; p += (size_t)(2 * DD) * (2 * DD) * 2;
    short* HThi  = (short*)p; p += (size_t)DD * (2 * DD) * 2;       // 1 MB (FO N=512,K=1024)
    short* HTlo  = (short*)p; p += (size_t)DD * (2 * DD) * 2;
    unsigned short* idx = (unsigned short*)p;
    p += (size_t)NNODE * NEDGE * MAXE * 2;                          // 3 MB
    int* cnt2 = (int*)p; p += (size_t)NNODE * NEDGE * 4;

    float* outF = (float*)d_out;

    k_init<<<NNODE, 256, 0, stream>>>(ann, h, HBhi, HBlo, cnt2);
    k_build<<<NNODE, 256, 0, stream>>>(adj, cnt2, idx);
    k_transP<<<dim3(KP / 32, DD / 32), 256, 0, stream>>>(Wp, WpThi, WpTlo, KP);
    k_transG<<<dim3(32, 32), 256, 0, stream>>>(Wz, Uz, Wr, Ur, ZRhi, ZRlo);
    k_transG<<<dim3(32, 16), 256, 0, stream>>>(Wh, Uh, Wh, Uh, HThi, HTlo);

    for (int s = 0; s < NSTEPS; s++) {
        k_gather_all<<<NNODE, 256, 0, stream>>>(h, cnt2, idx, bp, Gbhi, Gblo, abuf);
        // prop split-K: P0/P1 = Gbig @ WpT halves
        k_gemm8<0><<<1024, 256, 0, stream>>>(Gbhi, Gblo, nullptr, nullptr,
                                             WpThi, WpTlo, nullptr, nullptr,
                                             nullptr, nullptr, nullptr, nullptr, P0, P1);
        // Ga = split(P0 + P1 + deg-bias)
        k_combP<<<NNODE, 256, 0, stream>>>(P0, P1, abuf, Gahi, Galo);
        // [z|r]: z -> abuf (fp32), RH = split(sigmoid(.)*h)
        k_gemm8<1><<<1024, 256, 0, stream>>>(Gahi, Galo, HBhi, HBlo,
                                             ZRhi, ZRlo, bz, br,
                                             abuf, h, RHhi, RHlo, nullptr, nullptr);
        // fin split: P0 = Ga@Wh, P1 = RH@Uh
        k_gemm8<2><<<1024, 256, 0, stream>>>(Gahi, Galo, RHhi, RHlo,
                                             HThi, HTlo, nullptr, nullptr,
                                             nullptr, nullptr, nullptr, nullptr, P0, P1);
        // h' = (1-z)h + z*tanh(P0+P1+bh) -> h, HB, d_out
        k_combF<<<NNODE, 256, 0, stream>>>(P0, P1, bh, abuf, h, HBhi, HBlo, outF);
    }
}